// Round 1
// baseline (252.846 us; speedup 1.0000x reference)
//
#include <hip/hip_runtime.h>
#include <math.h>

// VQ quantizer: x [512,256,12] fp32, codebook [512,12] fp32.
// Outputs (concat fp32): quantized_st [512*256*12], indices-as-float [512*256], loss [1].
//
// R8 restructure: grid was 512 blocks = exactly 2 blocks/CU -> occupancy-capped
// (VALUBusy 43%, wall 3.3x the ~13.6us VALU issue floor). Split the codebook
// across blocks (KHALF=2): 1024 blocks x 512 thr, each scans 256 codes for 256
// tokens. Per-wave DS count and total VALU unchanged; resident waves 16->24/CU
// (launch_bounds(512,6) caps VGPR at 85; previous loop measured 84).
// Cross-block argmin combined in a second small pass that also does the
// gather/ST-write/loss epilogue. pack_cb folded into pass 1 (stage from cb +
// in-LDS w2, identical fmaf chain). Dispatches 3 -> 2.
namespace {
constexpr int KCB   = 512;
constexpr int DIM   = 12;
constexpr int NTOK  = 512 * 256;       // 131072
constexpr int QSIZE = NTOK * DIM;      // 1572864
constexpr int NSPLIT = 8;              // waves per block == K chunks within block
constexpr int KHALF  = 2;              // codebook halves across blocks
constexpr int KCODES = KCB / KHALF;    // 256 codes per block
constexpr int KCHUNK = KCODES / NSPLIT;// 32 codes per wave
constexpr int TPT    = 4;              // tokens/thread (keeps DS reads amortized 4x)
constexpr int TOKS_PER_BLOCK = 64 * TPT;        // 256
constexpr int NTG    = NTOK / TOKS_PER_BLOCK;   // 512 token groups
constexpr int NBLK1  = NTG * KHALF;             // 1024 blocks, pass 1
constexpr int WVEC   = KCODES * DIM;            // 3072 floats (tight 48B rows)
// shared: staging (3072 + 256 w2 = 3328 floats = 13312 B, in-loop prefetch
// overruns up to float idx 3328+7) aliased under the 8x256 u64 key area (16 KB).
constexpr int SMEM_U64 = NSPLIT * TOKS_PER_BLOCK;   // 2048 u64 = 16384 B
// ws layout: keys[2][NTOK] u64  (2 MB required)
constexpr int EMIT_THREADS = 256;
constexpr int NBLK2 = NTOK / EMIT_THREADS;      // 512 blocks, pass 2

// EXACT score sequence validated R1-R7 (absmax 0.0 vs numpy). Do not reorder.
__device__ inline float code_score(const float (&xv)[DIM], float x2,
                                   const float4& c0, const float4& c1,
                                   const float4& c2, float w2k) {
    float xw = 0.f;
    xw = fmaf(xv[0],  c0.x, xw);
    xw = fmaf(xv[1],  c0.y, xw);
    xw = fmaf(xv[2],  c0.z, xw);
    xw = fmaf(xv[3],  c0.w, xw);
    xw = fmaf(xv[4],  c1.x, xw);
    xw = fmaf(xv[5],  c1.y, xw);
    xw = fmaf(xv[6],  c1.z, xw);
    xw = fmaf(xv[7],  c1.w, xw);
    xw = fmaf(xv[8],  c2.x, xw);
    xw = fmaf(xv[9],  c2.y, xw);
    xw = fmaf(xv[10], c2.z, xw);
    xw = fmaf(xv[11], c2.w, xw);
    return fmaf(-2.f, xw, x2) + w2k;
}

// u64 (monotone(score), global k) unsigned-min == exact lexicographic
// first-occurrence argmin (validated R2-R7).
__device__ inline unsigned long long mkkey(float v, int k) {
    unsigned su = __float_as_uint(v);
    su = (su & 0x80000000u) ? ~su : (su | 0x80000000u);
    return ((unsigned long long)su << 32) | (unsigned)k;
}

// Pass 1: per (token-group, codebook-half) block, argmin over 256 codes for
// 256 tokens -> one u64 key per (half, token) in ws. No gather, no output.
// kh = bid>>9 so a token group's two blocks land on the same XCD L2 (x rows
// fetched once per XCD).
__global__ __launch_bounds__(512, 6) void vq_scan(const float* __restrict__ x,
                                                  const float* __restrict__ cb,
                                                  unsigned long long* __restrict__ keys,
                                                  float* __restrict__ out) {
    __shared__ unsigned long long smem[SMEM_U64];
    float* lds = (float*)smem;
    const int tid  = threadIdx.x;
    const int lane = tid & 63;
    const int s = __builtin_amdgcn_readfirstlane(tid >> 6);  // K-chunk id in block
    const int tg = blockIdx.x & (NTG - 1);
    const int kh = blockIdx.x >> 9;
    const int kbase = kh * KCODES;
    const int tbase = tg * TOKS_PER_BLOCK;

    // zero the loss accumulator for pass 2's atomics (pass 1 wholly precedes
    // pass 2 in the stream; robust against harness output re-poisoning).
    if (blockIdx.x == 0 && tid == 0) out[QSIZE + NTOK] = 0.f;

    // stage this block's half-codebook global->LDS (coalesced float4, rows tight)
    {
        const float4* g4 = (const float4*)(cb + (size_t)kbase * DIM);
        float4* l4 = (float4*)lds;
        for (int i = tid; i < WVEC / 4; i += 512) l4[i] = g4[i];
    }

    // this thread's 4 tokens (lane-contiguous 48B rows) — issued before the
    // staging barrier; independent of LDS.
    float xs[TPT][DIM];
    float x2[TPT];
#pragma unroll
    for (int j = 0; j < TPT; ++j) {
        const float4* xp = (const float4*)(x + (size_t)(tbase + j * 64 + lane) * DIM);
        float4 a0 = xp[0], a1 = xp[1], a2 = xp[2];
        xs[j][0] = a0.x; xs[j][1] = a0.y; xs[j][2]  = a0.z; xs[j][3]  = a0.w;
        xs[j][4] = a1.x; xs[j][5] = a1.y; xs[j][6]  = a1.z; xs[j][7]  = a1.w;
        xs[j][8] = a2.x; xs[j][9] = a2.y; xs[j][10] = a2.z; xs[j][11] = a2.w;
        float t2 = 0.f;
#pragma unroll
        for (int d = 0; d < DIM; ++d) t2 = fmaf(xs[j][d], xs[j][d], t2);
        x2[j] = t2;
    }

    __syncthreads();   // codebook rows resident

    // w2 per code, threads 0..255 — SAME fmaf chain as old pack_cb (bit-exact)
    if (tid < KCODES) {
        const float* w = lds + (size_t)tid * DIM;
        float w2 = 0.f;
#pragma unroll
        for (int d = 0; d < DIM; ++d) w2 = fmaf(w[d], w[d], w2);
        lds[WVEC + tid] = w2;
    }
    __syncthreads();   // w2 resident

    float best[TPT];
    int   bi[TPT];
#pragma unroll
    for (int j = 0; j < TPT; ++j) { best[j] = INFINITY; bi[j] = 0; }

    const int k0l = s * KCHUNK;          // local row in LDS
    const int gk0 = kbase + k0l;         // global code id of chunk start
    const float* w2v = lds + WVEC;

    // ---- software-pipelined scan: 2-code double buffer (R7 structure) ----
    float4 A0, A1, A2; float w2A;
    float4 B0, B1, B2; float w2B;
    {
        const float* c = lds + (size_t)k0l * DIM;
        A0 = *(const float4*)(c + 0);
        A1 = *(const float4*)(c + 4);
        A2 = *(const float4*)(c + 8);
        w2A = w2v[k0l];
    }
#pragma unroll 4
    for (int kk = 0; kk < KCHUNK; kk += 2) {
        {   // prefetch odd code kk+1 into B
            const float* c = lds + (size_t)(k0l + kk + 1) * DIM;
            B0 = *(const float4*)(c + 0);
            B1 = *(const float4*)(c + 4);
            B2 = *(const float4*)(c + 8);
            w2B = w2v[k0l + kk + 1];
        }
        {   // score even code kk with A
            const int k = gk0 + kk;
#pragma unroll
            for (int j = 0; j < TPT; ++j) {
                float d = code_score(xs[j], x2[j], A0, A1, A2, w2A);
                bool c = d < best[j];          // strict < => first occurrence
                best[j] = c ? d : best[j];
                bi[j]   = c ? k : bi[j];
            }
        }
        {   // prefetch next even code kk+2 into A (last iter reads row 256 ==
            // w2 region: in-bounds of the 16KB smem, loaded but never scored)
            const float* c = lds + (size_t)(k0l + kk + 2) * DIM;
            A0 = *(const float4*)(c + 0);
            A1 = *(const float4*)(c + 4);
            A2 = *(const float4*)(c + 8);
            w2A = w2v[k0l + kk + 2];   // idx <= 256 < 4096 floats: in-bounds
        }
        {   // score odd code kk+1 with B
            const int k = gk0 + kk + 1;
#pragma unroll
            for (int j = 0; j < TPT; ++j) {
                float d = code_score(xs[j], x2[j], B0, B1, B2, w2B);
                bool c = d < best[j];
                best[j] = c ? d : best[j];
                bi[j]   = c ? k : bi[j];
            }
        }
    }

    __syncthreads();   // done reading codebook before aliasing overwrite
#pragma unroll
    for (int j = 0; j < TPT; ++j)
        smem[s * TOKS_PER_BLOCK + j * 64 + lane] = mkkey(best[j], bi[j]);
    __syncthreads();

    // waves 0..3 fold the 8 in-block chunks for token group j==s and emit the
    // per-(half, token) key. Global-id keys make the cross-block min exact.
    if (s < TPT) {
        const int tok = s * 64 + lane;
        unsigned long long m = smem[tok];
#pragma unroll
        for (int r = 1; r < NSPLIT; ++r) {
            unsigned long long v = smem[r * TOKS_PER_BLOCK + tok];
            m = v < m ? v : m;
        }
        keys[(size_t)kh * NTOK + tbase + tok] = m;
    }
}

// Pass 2: per token, min over the two half-keys (equal score => half 0 has the
// smaller global k => smaller key: first-occurrence preserved), then gather +
// straight-through write + loss. Same arithmetic as the old epilogue.
__global__ __launch_bounds__(EMIT_THREADS) void vq_emit(const float* __restrict__ x,
                                                        const float* __restrict__ cb,
                                                        const unsigned long long* __restrict__ keys,
                                                        float* __restrict__ out) {
    __shared__ float lred[EMIT_THREADS / 64];
    const int t = blockIdx.x * EMIT_THREADS + threadIdx.x;

    unsigned long long m0 = keys[t];
    unsigned long long m1 = keys[(size_t)NTOK + t];
    unsigned long long m = m1 < m0 ? m1 : m0;

    const int bid = (int)(m & 0xffffffffULL);
    unsigned eu = (unsigned)(m >> 32);
    unsigned orig = (eu & 0x80000000u) ? (eu ^ 0x80000000u) : ~eu;
    const float bsc = __uint_as_float(orig);

    const float4* xp = (const float4*)(x + (size_t)t * DIM);
    float4 a0 = xp[0], a1 = xp[1], a2 = xp[2];
    float xv[DIM] = {a0.x, a0.y, a0.z, a0.w, a1.x, a1.y, a1.z, a1.w,
                     a2.x, a2.y, a2.z, a2.w};

    const float4* wrow = (const float4*)(cb + (size_t)bid * DIM);
    float4 q0 = wrow[0], q1 = wrow[1], q2 = wrow[2];
    float qs[DIM] = {q0.x, q0.y, q0.z, q0.w, q1.x, q1.y, q1.z, q1.w,
                     q2.x, q2.y, q2.z, q2.w};

    float4* qo = (float4*)(out + (size_t)t * DIM);
    float4 r0, r1, r2;
    r0.x = xv[0] + (qs[0] - xv[0]);    r0.y = xv[1] + (qs[1] - xv[1]);
    r0.z = xv[2] + (qs[2] - xv[2]);    r0.w = xv[3] + (qs[3] - xv[3]);
    r1.x = xv[4] + (qs[4] - xv[4]);    r1.y = xv[5] + (qs[5] - xv[5]);
    r1.z = xv[6] + (qs[6] - xv[6]);    r1.w = xv[7] + (qs[7] - xv[7]);
    r2.x = xv[8] + (qs[8] - xv[8]);    r2.y = xv[9] + (qs[9] - xv[9]);
    r2.z = xv[10] + (qs[10] - xv[10]); r2.w = xv[11] + (qs[11] - xv[11]);
    qo[0] = r0; qo[1] = r1; qo[2] = r2;

    out[QSIZE + t] = (float)bid;

    // loss partial: sum_d(q-x)^2 == best score (~1e-8 rel; thr ~2%).
    // per-wave shuffle sum -> per-block partial -> one atomicAdd per block
    // (accumulator zeroed by pass 1; add order reassociation ~1e-7 rel).
    float ls = bsc * (1.25f / (float)QSIZE);
#pragma unroll
    for (int off = 32; off > 0; off >>= 1) ls += __shfl_down(ls, off);
    if ((threadIdx.x & 63) == 0) lred[threadIdx.x >> 6] = ls;
    __syncthreads();
    if (threadIdx.x == 0) {
        float v = (lred[0] + lred[1]) + (lred[2] + lred[3]);
        atomicAdd(out + QSIZE + NTOK, v);
    }
}
} // namespace

extern "C" void kernel_launch(void* const* d_in, const int* in_sizes, int n_in,
                              void* d_out, int out_size, void* d_ws, size_t ws_size,
                              hipStream_t stream) {
    const float* x  = (const float*)d_in[0];
    const float* cb = (const float*)d_in[1];
    float* out = (float*)d_out;
    // ws: keys[2][NTOK] u64 = 2 MB
    unsigned long long* keys = (unsigned long long*)d_ws;

    vq_scan<<<NBLK1, 512, 0, stream>>>(x, cb, keys, out);
    vq_emit<<<NBLK2, EMIT_THREADS, 0, stream>>>(x, cb, keys, out);
}

// Round 2
// 88.848 us; speedup vs baseline: 2.8458x; 2.8458x over previous
//
#include <hip/hip_runtime.h>
#include <math.h>

// VQ quantizer: x [512,256,12] fp32, codebook [512,12] fp32.
// Outputs (concat fp32): quantized_st [512*256*12], indices-as-float [512*256], loss [1].
//
// R9: R8's launch_bounds(512,6) forced the allocator under the coarse 64-VGPR
// occupancy step -> 40 VGPR + inner-loop spills (FETCH 94 GB of scratch).
// Fix the state, not the bound: codebook rows are WAVE-UNIFORM -> load them
// via scalar (SGPR) loads from a padded 16-float-row pack, eliminating the
// 26-VGPR LDS double buffer, all ds_read convoying, and LDS staging entirely.
// TPT=2 (xs = 24 VGPR) -> ~45-50 VGPR total, under the 64-VGPR tier =>
// 8 waves/SIMD with 1024 blocks (4/CU exact). Full 512 codes stay in-block
// (8 waves x 64-code chunks over the same 128 tokens) -> no cross-block pass.
// launch_bounds(512,4) is a cap (128), never a spill-forcing demand.
namespace {
constexpr int KCB   = 512;
constexpr int DIM   = 12;
constexpr int NTOK  = 512 * 256;       // 131072
constexpr int QSIZE = NTOK * DIM;      // 1572864
constexpr int NSPLIT = 8;              // waves per block == K chunks
constexpr int KCHUNK = KCB / NSPLIT;   // 64 codes per wave
constexpr int TPT    = 2;              // tokens/thread (keeps VGPR <= 64 tier)
constexpr int TOKS_PER_BLOCK = 64 * TPT;        // 128
constexpr int NBLK   = NTOK / TOKS_PER_BLOCK;   // 1024 blocks x 512 thr = 4/CU
constexpr int ROWF   = 16;             // packed row: w[12], w2, pad[3] (64 B)
// ws layout: pk[513][16] floats (row 512 = zero pad for the tail prefetch)

// EXACT score sequence validated R1-R8 (absmax 0.0 vs numpy). Do not reorder.
__device__ inline float code_score(const float (&xv)[DIM], float x2,
                                   const float4& c0, const float4& c1,
                                   const float4& c2, float w2k) {
    float xw = 0.f;
    xw = fmaf(xv[0],  c0.x, xw);
    xw = fmaf(xv[1],  c0.y, xw);
    xw = fmaf(xv[2],  c0.z, xw);
    xw = fmaf(xv[3],  c0.w, xw);
    xw = fmaf(xv[4],  c1.x, xw);
    xw = fmaf(xv[5],  c1.y, xw);
    xw = fmaf(xv[6],  c1.z, xw);
    xw = fmaf(xv[7],  c1.w, xw);
    xw = fmaf(xv[8],  c2.x, xw);
    xw = fmaf(xv[9],  c2.y, xw);
    xw = fmaf(xv[10], c2.z, xw);
    xw = fmaf(xv[11], c2.w, xw);
    return fmaf(-2.f, xw, x2) + w2k;
}

// u64 (monotone(score), k) unsigned-min == exact lexicographic
// first-occurrence argmin (validated R2-R8).
__device__ inline unsigned long long mkkey(float v, int k) {
    unsigned su = __float_as_uint(v);
    su = (su & 0x80000000u) ? ~su : (su | 0x80000000u);
    return ((unsigned long long)su << 32) | (unsigned)k;
}

// Pack codebook into 64 B rows [w0..w11, w2, 0,0,0] (w2 = exact fmaf chain,
// same rounding as R1-R8). Also zeroes the loss accumulator (this dispatch
// precedes vq_main in-stream, so the zero is ordered before the atomics and
// re-runs on every graph replay after harness re-poisoning).
__global__ __launch_bounds__(256) void pack_cb(const float* __restrict__ cb,
                                               float* __restrict__ pk,
                                               float* __restrict__ out) {
    int k = blockIdx.x * blockDim.x + threadIdx.x;
    if (k == 0) out[QSIZE + NTOK] = 0.f;
    if (k >= KCB) return;
    float w[DIM];
#pragma unroll
    for (int d = 0; d < DIM; ++d) w[d] = cb[k * DIM + d];
    float w2 = 0.f;
#pragma unroll
    for (int d = 0; d < DIM; ++d) w2 = fmaf(w[d], w[d], w2);
#pragma unroll
    for (int d = 0; d < DIM; ++d) pk[k * ROWF + d] = w[d];
    pk[k * ROWF + 12] = w2;
    pk[k * ROWF + 13] = 0.f; pk[k * ROWF + 14] = 0.f; pk[k * ROWF + 15] = 0.f;
    if (k == KCB - 1) {  // zero pad row 512 (read by tail prefetch, never scored)
#pragma unroll
        for (int d = 0; d < ROWF; ++d) pk[KCB * ROWF + d] = 0.f;
    }
}

// Block = 128 tokens x 8 K-splits. Codebook read via wave-uniform (scalar)
// loads from pk; LDS used only for the 8 KB cross-wave key reduce.
__global__ __launch_bounds__(512, 4) void vq_main(const float* __restrict__ x,
                                                  const float* __restrict__ cb,
                                                  const float* __restrict__ pk,
                                                  float* __restrict__ out) {
    __shared__ unsigned long long keys[NSPLIT * TOKS_PER_BLOCK];  // 8 KB
    __shared__ float lred[TPT];
    const int tid  = threadIdx.x;
    const int lane = tid & 63;
    const int s = __builtin_amdgcn_readfirstlane(tid >> 6);  // K-chunk id
    const int tbase = blockIdx.x * TOKS_PER_BLOCK;

    // this thread's 2 tokens (lane-contiguous 48B rows)
    float xs[TPT][DIM];
    float x2[TPT];
#pragma unroll
    for (int j = 0; j < TPT; ++j) {
        const float4* xp = (const float4*)(x + (size_t)(tbase + j * 64 + lane) * DIM);
        float4 a0 = xp[0], a1 = xp[1], a2 = xp[2];
        xs[j][0] = a0.x; xs[j][1] = a0.y; xs[j][2]  = a0.z; xs[j][3]  = a0.w;
        xs[j][4] = a1.x; xs[j][5] = a1.y; xs[j][6]  = a1.z; xs[j][7]  = a1.w;
        xs[j][8] = a2.x; xs[j][9] = a2.y; xs[j][10] = a2.z; xs[j][11] = a2.w;
        float t2 = 0.f;
#pragma unroll
        for (int d = 0; d < DIM; ++d) t2 = fmaf(xs[j][d], xs[j][d], t2);
        x2[j] = t2;
    }

    float best[TPT];
    int   bi[TPT];
#pragma unroll
    for (int j = 0; j < TPT; ++j) { best[j] = INFINITY; bi[j] = 0; }

    const int k0 = s * KCHUNK;
    const float* cw = pk + (size_t)k0 * ROWF;   // wave-uniform base

    // ---- 2-code double buffer; all code values wave-uniform (SGPR-promotable)
    float4 A0, A1, A2; float w2A;
    float4 B0, B1, B2; float w2B;
    A0 = *(const float4*)(cw + 0);
    A1 = *(const float4*)(cw + 4);
    A2 = *(const float4*)(cw + 8);
    w2A = cw[12];
#pragma unroll 2
    for (int kk = 0; kk < KCHUNK; kk += 2) {
        {   // prefetch odd code kk+1 into B
            const float* c = cw + (size_t)(kk + 1) * ROWF;
            B0 = *(const float4*)(c + 0);
            B1 = *(const float4*)(c + 4);
            B2 = *(const float4*)(c + 8);
            w2B = c[12];
        }
        {   // score even code kk with A
            const int k = k0 + kk;
#pragma unroll
            for (int j = 0; j < TPT; ++j) {
                float d = code_score(xs[j], x2[j], A0, A1, A2, w2A);
                bool c = d < best[j];          // strict < => first occurrence
                best[j] = c ? d : best[j];
                bi[j]   = c ? k : bi[j];
            }
        }
        {   // prefetch next even code kk+2 into A (last iter reads the zero
            // pad row 512 for s=7 / next chunk's row otherwise: never scored)
            const float* c = cw + (size_t)(kk + 2) * ROWF;
            A0 = *(const float4*)(c + 0);
            A1 = *(const float4*)(c + 4);
            A2 = *(const float4*)(c + 8);
            w2A = c[12];
        }
        {   // score odd code kk+1 with B
            const int k = k0 + kk + 1;
#pragma unroll
            for (int j = 0; j < TPT; ++j) {
                float d = code_score(xs[j], x2[j], B0, B1, B2, w2B);
                bool c = d < best[j];
                best[j] = c ? d : best[j];
                bi[j]   = c ? k : bi[j];
            }
        }
    }

    // cross-wave argmin via u64 keys in LDS (global code ids 0..511)
#pragma unroll
    for (int j = 0; j < TPT; ++j)
        keys[s * TOKS_PER_BLOCK + j * 64 + lane] = mkkey(best[j], bi[j]);
    __syncthreads();

    // waves 0..1 finalize token group j==s (they hold xs[s] for those tokens)
    if (s < TPT) {
        const int tok = s * 64 + lane;
        unsigned long long m = keys[tok];
#pragma unroll
        for (int r = 1; r < NSPLIT; ++r) {
            unsigned long long v = keys[r * TOKS_PER_BLOCK + tok];
            m = v < m ? v : m;
        }
        const int bid = (int)(m & 0xffffffffULL);
        unsigned eu = (unsigned)(m >> 32);
        unsigned orig = (eu & 0x80000000u) ? (eu ^ 0x80000000u) : ~eu;
        const float bsc = __uint_as_float(orig);
        const int t = tbase + tok;

        float xv[DIM];
#pragma unroll
        for (int j = 0; j < TPT; ++j)
            if (j == s) {
#pragma unroll
                for (int d = 0; d < DIM; ++d) xv[d] = xs[j][d];
            }

        const float4* wrow = (const float4*)(cb + (size_t)bid * DIM);
        float4 q0 = wrow[0], q1 = wrow[1], q2 = wrow[2];
        float qs[DIM] = {q0.x, q0.y, q0.z, q0.w, q1.x, q1.y, q1.z, q1.w,
                         q2.x, q2.y, q2.z, q2.w};

        float4* qo = (float4*)(out + (size_t)t * DIM);
        float4 r0, r1, r2;
        r0.x = xv[0] + (qs[0] - xv[0]);    r0.y = xv[1] + (qs[1] - xv[1]);
        r0.z = xv[2] + (qs[2] - xv[2]);    r0.w = xv[3] + (qs[3] - xv[3]);
        r1.x = xv[4] + (qs[4] - xv[4]);    r1.y = xv[5] + (qs[5] - xv[5]);
        r1.z = xv[6] + (qs[6] - xv[6]);    r1.w = xv[7] + (qs[7] - xv[7]);
        r2.x = xv[8] + (qs[8] - xv[8]);    r2.y = xv[9] + (qs[9] - xv[9]);
        r2.z = xv[10] + (qs[10] - xv[10]); r2.w = xv[11] + (qs[11] - xv[11]);
        qo[0] = r0; qo[1] = r1; qo[2] = r2;

        out[QSIZE + t] = (float)bid;

        // loss partial: sum_d(q-x)^2 == best score (~1e-8 rel; thr ~2%).
        float ls = bsc * (1.25f / (float)QSIZE);
#pragma unroll
        for (int off = 32; off > 0; off >>= 1) ls += __shfl_down(ls, off);
        if (lane == 0) lred[s] = ls;
    }
    __syncthreads();
    // one fp32 atomic per block (accumulator zeroed by pack_cb; order
    // reassociation ~1e-7 rel, far under the ~2% loss threshold)
    if (tid == 0) atomicAdd(out + QSIZE + NTOK, lred[0] + lred[1]);
}
} // namespace

extern "C" void kernel_launch(void* const* d_in, const int* in_sizes, int n_in,
                              void* d_out, int out_size, void* d_ws, size_t ws_size,
                              hipStream_t stream) {
    const float* x  = (const float*)d_in[0];
    const float* cb = (const float*)d_in[1];
    float* out = (float*)d_out;
    float* pk  = (float*)d_ws;   // packed codebook: 513 x 16 floats = 32.8 KB

    pack_cb<<<2, 256, 0, stream>>>(cb, pk, out);
    vq_main<<<NBLK, 512, 0, stream>>>(x, cb, pk, out);
}